// Round 1
// baseline (128.506 us; speedup 1.0000x reference)
//
#include <hip/hip_runtime.h>

#define NB 16      // batch
#define NS 512     // tokens
#define ND 384     // hidden dim
#define K4 (ND/4)  // float4s per row = 96
#define NT 256     // threads per block (4 waves)
#define GROWS 32   // output rows per gather block (12 float4/thread)
#define FROWS 16   // rows per block for fused fallback (previous best)

typedef float vf4 __attribute__((ext_vector_type(4)));

// ---------------------------------------------------------------------------
// Phase 1: one block per batch. Scan the 512 durations ONCE, scatter the
// row->token map into workspace, write out_lengths. ~5 us total (16 blocks).
// Replaces the scan that the fused kernel redid in all ~250 window-blocks.
// ---------------------------------------------------------------------------
__global__ __launch_bounds__(NT) void build_map(
    const int* __restrict__ dur,       // [B*S]
    int*       __restrict__ rowMap,    // [B*L] workspace
    float*     __restrict__ outLenF,   // [B]
    int L)
{
    const int t = threadIdx.x;
    const int b = blockIdx.x;
    __shared__ int wsum[NT / 64];

    // 2 durations per thread, shfl-scan + wave-combine (proven in fused ver.)
    int2 d2 = ((const int2*)(dur + b * NS))[t];   // tokens 2t, 2t+1
    int local = d2.x + d2.y;
    int lane = t & 63, wave = t >> 6;
    int x = local;
    #pragma unroll
    for (int off = 1; off < 64; off <<= 1) {
        int y = __shfl_up(x, off, 64);
        if (lane >= off) x += y;
    }
    if (lane == 63) wsum[wave] = x;
    __syncthreads();
    int wbase = 0, total = 0;
    #pragma unroll
    for (int w = 0; w < NT / 64; ++w) {
        int s = wsum[w];
        if (w < wave) wbase += s;
        total += s;
    }
    int excl = wbase + x - local;                 // exclusive prefix of token 2t

    // Scatter: token s owns output rows [excl_s, excl_s + dur_s). Ranges
    // partition [0,total) exactly (dur==0 tokens write nothing), matching
    // searchsorted(side='right'). ~3840 scattered int writes per batch: tiny.
    int* map = rowMap + (size_t)b * L;
    int e0 = excl,        n0 = d2.x;
    int e1 = excl + d2.x, n1 = d2.y;
    for (int j = e0; j < e0 + n0; ++j) map[j] = 2 * t;
    for (int j = e1; j < e1 + n1; ++j) map[j] = 2 * t + 1;
    // -1 tail => gather writes zeros (torch zero-init semantics)
    for (int j = total + t; j < L; j += NT) map[j] = -1;

    if (t == 0) outLenF[b] = (float)total;        // harness reads flat f32
}

// ---------------------------------------------------------------------------
// Phase 2: pure streaming gather. No scan, no barriers, no LDS.
// grid (ceil(L/GROWS), NB). Per block: GROWS*96 = 3072 float4s, 12/thread.
// map[r] reads are wave-broadcast L1 hits; writes are contiguous 16B/lane,
// nontemporal (output is never re-read -> don't evict hidden from L2).
// ---------------------------------------------------------------------------
__global__ __launch_bounds__(NT) void gather_rows(
    const vf4* __restrict__ hidden4,   // [B*S*96]
    const int* __restrict__ rowMap,    // [B*L]
    vf4*       __restrict__ out4,      // [B*L*96]
    int L)
{
    const int t  = threadIdx.x;
    const int b  = blockIdx.y;
    const int j0 = blockIdx.x * GROWS;
    const int* __restrict__ map = rowMap + (size_t)b * L + j0;
    const size_t outBase = ((size_t)b * L + j0) * K4;
    const size_t hidBase = (size_t)b * NS * K4;

    if (j0 + GROWS <= L) {
        // full window: branch-free hot path
        #pragma unroll
        for (int i = 0; i < GROWS * K4 / NT; ++i) {   // 12 iterations
            int idx = t + i * NT;
            int r = idx / K4;                          // const div -> magic mul
            int k = idx - r * K4;
            int g = map[r];
            vf4 v = {0.f, 0.f, 0.f, 0.f};
            if (g >= 0) v = hidden4[hidBase + (size_t)g * K4 + k];
            __builtin_nontemporal_store(v, &out4[outBase + idx]);
        }
    } else {
        const int rmax = L - j0;                       // tail window
        #pragma unroll
        for (int i = 0; i < GROWS * K4 / NT; ++i) {
            int idx = t + i * NT;
            int r = idx / K4;
            int k = idx - r * K4;
            if (r >= rmax) break;                      // r monotonic in i
            int g = map[r];
            vf4 v = {0.f, 0.f, 0.f, 0.f};
            if (g >= 0) v = hidden4[hidBase + (size_t)g * K4 + k];
            __builtin_nontemporal_store(v, &out4[outBase + idx]);
        }
    }
}

// ---------------------------------------------------------------------------
// Fallback: previous best fused kernel (R2 shape), used only if ws_size is
// too small to hold the [B*L] row map.
// ---------------------------------------------------------------------------
__global__ __launch_bounds__(NT) void length_regulator_fused(
    const float4* __restrict__ hidden4,
    const int*    __restrict__ dur,
    float4*       __restrict__ out4,
    float*        __restrict__ outLenF,
    int L)
{
    const int t = threadIdx.x;
    const int b = blockIdx.y;
    const int j0 = blockIdx.x * FROWS;

    __shared__ int wsum[NT / 64];
    __shared__ int rowTok[FROWS];

    if (t < FROWS) rowTok[t] = -1;

    int2 d2 = ((const int2*)(dur + b * NS))[t];
    int local = d2.x + d2.y;
    int lane = t & 63, wave = t >> 6;
    int x = local;
    #pragma unroll
    for (int off = 1; off < 64; off <<= 1) {
        int y = __shfl_up(x, off, 64);
        if (lane >= off) x += y;
    }
    if (lane == 63) wsum[wave] = x;
    __syncthreads();
    int wbase = 0, total = 0;
    #pragma unroll
    for (int w = 0; w < NT / 64; ++w) {
        int s = wsum[w];
        if (w < wave) wbase += s;
        total += s;
    }
    int excl = wbase + x - local;

    {
        int e0 = excl,        n0 = d2.x;
        int e1 = excl + d2.x, n1 = d2.y;
        int lo0 = max(e0, j0), hi0 = min(e0 + n0, j0 + FROWS);
        for (int j = lo0; j < hi0; ++j) rowTok[j - j0] = 2 * t;
        int lo1 = max(e1, j0), hi1 = min(e1 + n1, j0 + FROWS);
        for (int j = lo1; j < hi1; ++j) rowTok[j - j0] = 2 * t + 1;
    }
    __syncthreads();

    if (j0 == 0 && t == 0) outLenF[b] = (float)total;

    const size_t outBase = ((size_t)b * L + j0) * K4;
    const size_t hidBase = (size_t)b * NS * K4;
    #pragma unroll
    for (int i = t; i < FROWS * K4; i += NT) {
        int r = i / K4;
        int k = i - r * K4;
        if (j0 + r >= L) break;
        int g = rowTok[r];
        float4 v;
        if (g < 0) v = make_float4(0.f, 0.f, 0.f, 0.f);
        else       v = hidden4[hidBase + (size_t)g * K4 + k];
        out4[outBase + i] = v;
    }
}

extern "C" void kernel_launch(void* const* d_in, const int* in_sizes, int n_in,
                              void* d_out, int out_size, void* d_ws, size_t ws_size,
                              hipStream_t stream) {
    const float* hidden    = (const float*)d_in[0];
    const int*   durations = (const int*)d_in[1];
    float* out = (float*)d_out;

    // out_size = B*L*D + B (floats)
    int L = (out_size - NB) / (NB * ND);
    float* outLenF = out + (size_t)NB * L * ND;

    size_t mapBytes = (size_t)NB * L * sizeof(int);
    if (ws_size >= mapBytes) {
        int* rowMap = (int*)d_ws;
        build_map<<<dim3(NB), NT, 0, stream>>>(durations, rowMap, outLenF, L);
        dim3 grid((L + GROWS - 1) / GROWS, NB);
        gather_rows<<<grid, NT, 0, stream>>>(
            (const vf4*)hidden, rowMap, (vf4*)out, L);
    } else {
        dim3 grid((L + FROWS - 1) / FROWS, NB);
        length_regulator_fused<<<grid, NT, 0, stream>>>(
            (const float4*)hidden, durations, (float4*)out, outLenF, L);
    }
}

// Round 2
// 117.319 us; speedup vs baseline: 1.0954x; 1.0954x over previous
//
#include <hip/hip_runtime.h>

#define NB 16      // batch
#define NS 512     // tokens
#define ND 384     // hidden dim
#define K4 (ND/4)  // float4s per row = 96
#define ROWS 16    // output rows per block (best measured shape)
#define NT 256     // threads per block (4 waves)

// Fused length-regulator (reverted round-0 kernel — measured at the write
// roofline). The output buffer is 397 MB (L≈16164); the kernel streams it at
// ~6.8 TB/s effective, matching the harness's own 397 MB poison fill (62 us).
// Scan/barrier/shape changes are all neutral (round-1 A/B): write-BW-bound.
__global__ __launch_bounds__(NT) void length_regulator_fused(
    const float4* __restrict__ hidden4,   // [B*S*96]
    const int*    __restrict__ dur,       // [B*S]
    float4*       __restrict__ out4,      // [B*L*96]
    float*        __restrict__ outLenF,   // [B], after out4 region
    int L)
{
    const int t = threadIdx.x;
    const int b = blockIdx.y;
    const int j0 = blockIdx.x * ROWS;

    __shared__ int wsum[NT / 64];
    __shared__ int rowTok[ROWS];

    // ---- init rowTok to -1 (zero-pad sentinel) ----
    if (t < ROWS) rowTok[t] = -1;

    // ---- scan: 2 durations per thread ----
    int2 d2 = ((const int2*)(dur + b * NS))[t];   // tokens 2t, 2t+1
    int local = d2.x + d2.y;
    int lane = t & 63, wave = t >> 6;
    int x = local;
    #pragma unroll
    for (int off = 1; off < 64; off <<= 1) {
        int y = __shfl_up(x, off, 64);
        if (lane >= off) x += y;
    }
    if (lane == 63) wsum[wave] = x;
    __syncthreads();
    // every thread: prefix of waves below it AND the full batch total
    int wbase = 0, total = 0;
    #pragma unroll
    for (int w = 0; w < NT / 64; ++w) {
        int s = wsum[w];
        if (w < wave) wbase += s;
        total += s;
    }
    int excl = wbase + x - local;                 // exclusive prefix of token 2t

    // ---- intersect-scatter: token s covers rows [excl_s, excl_s + dur_s) ----
    {
        int e0 = excl,        n0 = d2.x;          // token 2t
        int e1 = excl + d2.x, n1 = d2.y;          // token 2t+1
        int lo0 = max(e0, j0), hi0 = min(e0 + n0, j0 + ROWS);
        for (int j = lo0; j < hi0; ++j) rowTok[j - j0] = 2 * t;
        int lo1 = max(e1, j0), hi1 = min(e1 + n1, j0 + ROWS);
        for (int j = lo1; j < hi1; ++j) rowTok[j - j0] = 2 * t + 1;
    }
    __syncthreads();

    if (j0 == 0 && t == 0) outLenF[b] = (float)total;

    // ---- gather / store: ROWS*96 = 1536 float4s, 6 per thread, coalesced ----
    const size_t outBase = ((size_t)b * L + j0) * K4;
    const size_t hidBase = (size_t)b * NS * K4;
    #pragma unroll
    for (int i = t; i < ROWS * K4; i += NT) {
        int r = i / K4;                           // const divisor -> magic mul
        int k = i - r * K4;
        if (j0 + r >= L) break;                   // tail window guard (r monotonic)
        int g = rowTok[r];
        float4 v;
        if (g < 0) v = make_float4(0.f, 0.f, 0.f, 0.f);
        else       v = hidden4[hidBase + (size_t)g * K4 + k];
        out4[outBase + i] = v;
    }
}

extern "C" void kernel_launch(void* const* d_in, const int* in_sizes, int n_in,
                              void* d_out, int out_size, void* d_ws, size_t ws_size,
                              hipStream_t stream) {
    const float* hidden    = (const float*)d_in[0];
    const int*   durations = (const int*)d_in[1];
    float* out = (float*)d_out;

    // out_size = B*L*D + B
    int L = (out_size - NB) / (NB * ND);
    float* outLenF = out + (size_t)NB * L * ND;

    dim3 grid((L + ROWS - 1) / ROWS, NB);
    length_regulator_fused<<<grid, NT, 0, stream>>>(
        (const float4*)hidden, durations, (float4*)out, outLenF, L);
}